// Round 9
// baseline (259.086 us; speedup 1.0000x reference)
//
#include <hip/hip_runtime.h>
#include <hip/hip_bf16.h>

#define BDIM 2
#define TDIM 2048
#define DDIM 1024
#define HH 4
#define KD 512
#define VD 1024
#define DK 128
#define DV 256
#define NC 32
#define CHUNKC 64
#define MTOT (BDIM*TDIM)   // 4096
#define NALL 3584          // q|k (1024) | gk (512) | v|g (2048)
#define STRIDE_ST ((size_t)BDIM*HH*DK*DV)   // 262144 elems per chunk of states

typedef __bf16 bf16x8 __attribute__((ext_vector_type(8)));
typedef float  f32x4  __attribute__((ext_vector_type(4)));
typedef __hip_bfloat16 hbf;

__device__ __forceinline__ void async_copy16(const void* g, void* l) {
  __builtin_amdgcn_global_load_lds(
      (const __attribute__((address_space(1))) void*)g,
      (__attribute__((address_space(3))) void*)l, 16, 0, 0);
}

// ---------------- cast x (fp32 -> bf16), 4 elems/thread ----------------
__global__ void cast_bf16_kernel(const float* __restrict__ src, hbf* __restrict__ dst) {
  int t = blockIdx.x*256 + threadIdx.x;
  float4 v = ((const float4*)src)[t];
  union { hbf h[4]; uint2 u; } o;
  o.h[0] = __float2bfloat16(v.x); o.h[1] = __float2bfloat16(v.y);
  o.h[2] = __float2bfloat16(v.z); o.h[3] = __float2bfloat16(v.w);
  ((uint2*)dst)[t] = o.u;
}

// ---------------- one-shot weight prep: transpose+cast all W, compute Wc^T ----
__global__ void prep_weights(const float* __restrict__ Wq, const float* __restrict__ Wk,
                             const float* __restrict__ Wv, const float* __restrict__ Wg,
                             const float* __restrict__ Wo, const float* __restrict__ W1,
                             const float* __restrict__ W2,
                             hbf* __restrict__ wtall, hbf* __restrict__ wto) {
  __shared__ float tile[32][33];
  const int n0 = blockIdx.x*32, k0 = blockIdx.y*32;
  const int tx = threadIdx.x & 31, ty = threadIdx.x >> 5;
  if (n0 >= 1024 && n0 < 1536) {          // Wc = (Wgk1 @ Wgk2)^T
    #pragma unroll
    for (int r = ty; r < 32; r += 8) {
      int n = n0 - 1024 + r, k = k0 + tx;
      float s = 0.f;
      #pragma unroll
      for (int j = 0; j < 16; ++j) s += W1[(size_t)k*16 + j] * W2[(size_t)j*KD + n];
      wtall[(size_t)(n0 + r)*DDIM + k] = __float2bfloat16(s);
    }
    return;
  }
  const float* W; int Nsrc, nloc; hbf* outp; int orow;
  if      (n0 < 512)  { W = Wq; Nsrc = 512;  nloc = n0;        outp = wtall; orow = n0; }
  else if (n0 < 1024) { W = Wk; Nsrc = 512;  nloc = n0 - 512;  outp = wtall; orow = n0; }
  else if (n0 < 2560) { W = Wv; Nsrc = 1024; nloc = n0 - 1536; outp = wtall; orow = n0; }
  else if (n0 < 3584) { W = Wg; Nsrc = 1024; nloc = n0 - 2560; outp = wtall; orow = n0; }
  else                { W = Wo; Nsrc = 1024; nloc = n0 - 3584; outp = wto;   orow = n0 - 3584; }
  #pragma unroll
  for (int r = ty; r < 32; r += 8)
    tile[r][tx] = W[(size_t)(k0 + r)*Nsrc + nloc + tx];
  __syncthreads();
  #pragma unroll
  for (int r = ty; r < 32; r += 8)
    outp[(size_t)(orow + r)*DDIM + k0 + tx] = __float2bfloat16(tile[tx][r]);
}

// LDS chunk swizzle: lane l stages logical 16B-chunk ((l&3)-(l>>4))&3; a fragment
// read of logical chunk q at row r uses physical chunk (q + ((r&15)>>2))&3.
// Makes every wave ds_read_b128 conflict-free (64 distinct row/chunk pairs).

// ---------------- projection GEMM: 128x256 tile, BK=64, swizzled LDS ----------
// C epilogue: n<1024 -> qk bf16 | n<1536 -> G fp32 | else vg bf16. K=DDIM fixed.
__global__ __launch_bounds__(256) void gemm_proj(const hbf* __restrict__ A,
                                                 const hbf* __restrict__ Bt,
                                                 float* __restrict__ Cf,
                                                 hbf* __restrict__ Cq,
                                                 hbf* __restrict__ Cv) {
  const int K = DDIM;
  __shared__ hbf As0[128][32], As1[128][32];
  __shared__ hbf Bs0[256][32], Bs1[256][32];
  const int t = threadIdx.x;
  const int w = t >> 6, l = t & 63;
  const int lr = l >> 2;
  const int srcc = (((l & 3) - (l >> 4)) & 3) * 8;   // swizzled source chunk
  const int lane16 = l & 15, quad = l >> 4;
  const int sw = ((lane16 >> 2)) & 3;                 // row-dependent rotation
  const int row0 = blockIdx.y*128, col0 = blockIdx.x*256;
  const int mb = (w >> 1)*64, nb = (w & 1)*128;

  const hbf* ga = A  + (size_t)(row0 + w*32 + lr)*K + srcc;
  const hbf* gb = Bt + (size_t)(col0 + w*64 + lr)*K + srcc;
  hbf* la0 = &As0[w*32][0];   hbf* la1 = &As0[w*32 + 16][0];
  hbf* la2 = &As1[w*32][0];   hbf* la3 = &As1[w*32 + 16][0];
  const size_t rstep = (size_t)16*K;

  f32x4 acc[4][8] = {};
  for (int k0 = 0; k0 < K; k0 += 64) {
    async_copy16(ga,              la0);
    async_copy16(ga + rstep,      la1);
    async_copy16(ga + 32,         la2);
    async_copy16(ga + rstep + 32, la3);
    #pragma unroll
    for (int rr = 0; rr < 4; ++rr) {
      async_copy16(gb + rstep*rr,      &Bs0[w*64 + rr*16][0]);
      async_copy16(gb + rstep*rr + 32, &Bs1[w*64 + rr*16][0]);
    }
    ga += 64; gb += 64;
    __syncthreads();
    {
      bf16x8 af[4], bfr[8];
      #pragma unroll
      for (int i = 0; i < 4; ++i)
        af[i] = *(const bf16x8*)&As0[mb + i*16 + lane16][((quad + sw) & 3)*8];
      #pragma unroll
      for (int j = 0; j < 8; ++j)
        bfr[j] = *(const bf16x8*)&Bs0[nb + j*16 + lane16][((quad + sw) & 3)*8];
      #pragma unroll
      for (int i = 0; i < 4; ++i)
        #pragma unroll
        for (int j = 0; j < 8; ++j)
          acc[i][j] = __builtin_amdgcn_mfma_f32_16x16x32_bf16(af[i], bfr[j], acc[i][j], 0, 0, 0);
    }
    {
      bf16x8 af[4], bfr[8];
      #pragma unroll
      for (int i = 0; i < 4; ++i)
        af[i] = *(const bf16x8*)&As1[mb + i*16 + lane16][((quad + sw) & 3)*8];
      #pragma unroll
      for (int j = 0; j < 8; ++j)
        bfr[j] = *(const bf16x8*)&Bs1[nb + j*16 + lane16][((quad + sw) & 3)*8];
      #pragma unroll
      for (int i = 0; i < 4; ++i)
        #pragma unroll
        for (int j = 0; j < 8; ++j)
          acc[i][j] = __builtin_amdgcn_mfma_f32_16x16x32_bf16(af[i], bfr[j], acc[i][j], 0, 0, 0);
    }
    __syncthreads();
  }
  #pragma unroll
  for (int i = 0; i < 4; ++i)
    #pragma unroll
    for (int j = 0; j < 8; ++j)
      #pragma unroll
      for (int r = 0; r < 4; ++r) {
        int m = row0 + mb + i*16 + quad*4 + r;
        int n = col0 + nb + j*16 + lane16;
        float v = acc[i][j][r];
        if (n < 1024)       Cq[(size_t)m*1024 + n] = __float2bfloat16(v);
        else if (n < 1536)  Cf[(size_t)m*512  + n - 1024] = v;
        else                Cv[(size_t)m*2048 + n - 1536] = __float2bfloat16(v);
      }
}

// ---------------- final GEMM: 128x128 tile, BK=64, swizzled LDS, fp32 C ------
__global__ __launch_bounds__(256) void gemm_bt(const hbf* __restrict__ A,
                                               const hbf* __restrict__ Bt,
                                               float* __restrict__ Cf,
                                               int M, int N, int K) {
  __shared__ hbf As0[128][32], As1[128][32];
  __shared__ hbf Bs0[128][32], Bs1[128][32];
  const int t = threadIdx.x;
  const int w = t >> 6, l = t & 63;
  const int lr = l >> 2;
  const int srcc = (((l & 3) - (l >> 4)) & 3) * 8;
  const int lane16 = l & 15, quad = l >> 4;
  const int sw = (lane16 >> 2) & 3;
  const int row0 = blockIdx.y*128, col0 = blockIdx.x*128;
  const int mb = (w >> 1)*64, nb = (w & 1)*64;

  const hbf* ga = A  + (size_t)(row0 + w*32 + lr)*K + srcc;
  const hbf* gb = Bt + (size_t)(col0 + w*32 + lr)*K + srcc;
  hbf* la0 = &As0[w*32][0];   hbf* la1 = &As0[w*32 + 16][0];
  hbf* la2 = &As1[w*32][0];   hbf* la3 = &As1[w*32 + 16][0];
  hbf* lb0 = &Bs0[w*32][0];   hbf* lb1 = &Bs0[w*32 + 16][0];
  hbf* lb2 = &Bs1[w*32][0];   hbf* lb3 = &Bs1[w*32 + 16][0];
  const size_t rstep = (size_t)16*K;

  f32x4 acc[4][4] = {};
  for (int k0 = 0; k0 < K; k0 += 64) {
    async_copy16(ga,              la0);
    async_copy16(ga + rstep,      la1);
    async_copy16(ga + 32,         la2);
    async_copy16(ga + rstep + 32, la3);
    async_copy16(gb,              lb0);
    async_copy16(gb + rstep,      lb1);
    async_copy16(gb + 32,         lb2);
    async_copy16(gb + rstep + 32, lb3);
    ga += 64; gb += 64;
    __syncthreads();
    {
      bf16x8 af[4], bfr[4];
      #pragma unroll
      for (int i = 0; i < 4; ++i)
        af[i] = *(const bf16x8*)&As0[mb + i*16 + lane16][((quad + sw) & 3)*8];
      #pragma unroll
      for (int j = 0; j < 4; ++j)
        bfr[j] = *(const bf16x8*)&Bs0[nb + j*16 + lane16][((quad + sw) & 3)*8];
      #pragma unroll
      for (int i = 0; i < 4; ++i)
        #pragma unroll
        for (int j = 0; j < 4; ++j)
          acc[i][j] = __builtin_amdgcn_mfma_f32_16x16x32_bf16(af[i], bfr[j], acc[i][j], 0, 0, 0);
    }
    {
      bf16x8 af[4], bfr[4];
      #pragma unroll
      for (int i = 0; i < 4; ++i)
        af[i] = *(const bf16x8*)&As1[mb + i*16 + lane16][((quad + sw) & 3)*8];
      #pragma unroll
      for (int j = 0; j < 4; ++j)
        bfr[j] = *(const bf16x8*)&Bs1[nb + j*16 + lane16][((quad + sw) & 3)*8];
      #pragma unroll
      for (int i = 0; i < 4; ++i)
        #pragma unroll
        for (int j = 0; j < 4; ++j)
          acc[i][j] = __builtin_amdgcn_mfma_f32_16x16x32_bf16(af[i], bfr[j], acc[i][j], 0, 0, 0);
    }
    __syncthreads();
  }
  #pragma unroll
  for (int i = 0; i < 4; ++i)
    #pragma unroll
    for (int j = 0; j < 4; ++j)
      #pragma unroll
      for (int r = 0; r < 4; ++r) {
        int m = row0 + mb + i*16 + quad*4 + r;
        int n = col0 + nb + j*16 + lane16;
        Cf[(size_t)m*N + n] = acc[i][j][r];
      }
}

// ---------------- fused: G = cumsum(log_sigmoid(pre + b)/16) in place on Gb ----
__global__ __launch_bounds__(256) void gkcumsum_kernel(float* __restrict__ Gb,
                                                       const float* __restrict__ bias) {
  __shared__ float buf[CHUNKC][128];
  const int cs = blockIdx.x & 3;
  const int nc = (blockIdx.x >> 2) & 31;
  const int b  = blockIdx.x >> 7;
  const int t = threadIdx.x;
  const int bc = b*TDIM + nc*CHUNKC;
  const int col0 = cs*128;
  #pragma unroll
  for (int i = 0; i < 32; ++i) {
    int idx = t + 256*i;
    int c = idx >> 7, col = idx & 127;
    float s = Gb[(size_t)(bc + c)*KD + col0 + col] + bias[col0 + col];
    float ls = fminf(s, 0.f) - log1pf(expf(-fabsf(s)));
    buf[c][col] = ls * (1.0f/16.0f);
  }
  __syncthreads();
  if (t < 128) {
    float acc = 0.f;
    #pragma unroll
    for (int c = 0; c < CHUNKC; ++c) {
      acc += buf[c][t];
      buf[c][t] = acc;
    }
  }
  __syncthreads();
  #pragma unroll
  for (int i = 0; i < 32; ++i) {
    int idx = t + 256*i;
    int c = idx >> 7, col = idx & 127;
    Gb[(size_t)(bc + c)*KD + col0 + col] = buf[c][col];
  }
}

// ---------------- per-chunk state increment (MFMA): U[v][k] bf16 ----------------
__global__ __launch_bounds__(256) void state_chunk_kernel(const hbf* __restrict__ qkbf,
                                                          const hbf* __restrict__ vgbf,
                                                          const float* __restrict__ Gb,
                                                          hbf* __restrict__ Ub,
                                                          float* __restrict__ dec) {
  const int bh = blockIdx.x & 7;
  const int nc = blockIdx.x >> 3;
  const int b = bh >> 2, h = bh & 3;
  const int t = threadIdx.x;
  const int w = t >> 6, l = t & 63;
  const int lane16 = l & 15, quad = l >> 4;
  __shared__ hbf kbarT[DK][72];     // [k][c]
  __shared__ hbf vT[DV][72];        // [v][c]
  __shared__ float glast[DK];
  const int bc = b*TDIM + nc*CHUNKC;
  if (t < DK) {
    float gl = Gb[(size_t)(bc + 63)*KD + h*DK + t];
    glast[t] = gl;
    dec[((size_t)nc*8 + bh)*DK + t] = expf(gl);
  }
  __syncthreads();
  #pragma unroll
  for (int i = 0; i < 32; ++i) {
    int idx = t + 256*i;
    int c = idx >> 7, kk = idx & 127;
    float g  = Gb[(size_t)(bc + c)*KD + h*DK + kk];
    float kv = __bfloat162float(qkbf[(size_t)(bc + c)*1024 + 512 + h*DK + kk]);
    kbarT[kk][c] = __float2bfloat16(kv * expf(glast[kk] - g));
  }
  #pragma unroll
  for (int i = 0; i < 64; ++i) {
    int idx = t + 256*i;
    int c = idx >> 8, col = idx & 255;
    vT[col][c] = vgbf[(size_t)(bc + c)*2048 + h*DV + col];
  }
  __syncthreads();
  f32x4 acc[4][8] = {};
  #pragma unroll
  for (int kc = 0; kc < 2; ++kc) {
    bf16x8 av[4], bk[8];
    #pragma unroll
    for (int i = 0; i < 4; ++i)
      av[i] = *(const bf16x8*)&vT[w*64 + i*16 + lane16][kc*32 + quad*8];
    #pragma unroll
    for (int j = 0; j < 8; ++j)
      bk[j] = *(const bf16x8*)&kbarT[j*16 + lane16][kc*32 + quad*8];
    #pragma unroll
    for (int i = 0; i < 4; ++i)
      #pragma unroll
      for (int j = 0; j < 8; ++j)
        acc[i][j] = __builtin_amdgcn_mfma_f32_16x16x32_bf16(av[i], bk[j], acc[i][j], 0, 0, 0);
  }
  hbf* ub = Ub + ((size_t)nc*8 + bh)*((size_t)DK*DV);
  #pragma unroll
  for (int i = 0; i < 4; ++i)
    #pragma unroll
    for (int j = 0; j < 8; ++j)
      #pragma unroll
      for (int r = 0; r < 4; ++r) {
        int v = w*64 + i*16 + quad*4 + r;
        int k = j*16 + lane16;
        ub[(size_t)v*DK + k] = __float2bfloat16(acc[i][j][r]);
      }
}

// ---------------- scan over chunks: reads U bf16, fp32 accum, writes S_prev bf16 ----
__global__ __launch_bounds__(256) void state_scan_kernel(const hbf* __restrict__ Ub,
                                                         const float* __restrict__ dec,
                                                         hbf* __restrict__ Spb) {
  const int p = blockIdx.x*256 + threadIdx.x;   // pair index 0..131071
  const size_t e = (size_t)p*2;
  const int k = (int)(e & 127);
  const int bh = (int)(e >> 15);
  float S0 = 0.f, S1 = 0.f;
  for (int nc = 0; nc < NC; ++nc) {
    const size_t off = (size_t)nc*STRIDE_ST + e;
    uint uu = *(const uint*)(Ub + off);
    hbf u0 = *(const hbf*)&uu;
    hbf u1 = *((const hbf*)&uu + 1);
    union { hbf h[2]; uint u; } ov;
    ov.h[0] = __float2bfloat16(S0); ov.h[1] = __float2bfloat16(S1);
    *(uint*)(Spb + off) = ov.u;
    float2 d = *(const float2*)(dec + ((size_t)nc*8 + bh)*DK + k);
    S0 = S0 * d.x + __bfloat162float(u0);
    S1 = S1 * d.y + __bfloat162float(u1);
  }
}

// ---------------- per-chunk output (MFMA): tril(qg kg^T), qg@S + A@v, RMSNorm, gate ----
__global__ __launch_bounds__(256) void out_kernel(const hbf* __restrict__ qkbf,
                                                  const hbf* __restrict__ vgbf,
                                                  const float* __restrict__ Gb,
                                                  const hbf* __restrict__ Spb,
                                                  const float* __restrict__ gnw,
                                                  hbf* __restrict__ obf) {
  const int blk = blockIdx.x;
  const int h = blk & 3, b = (blk >> 2) & 1, nc = blk >> 3;
  const int t = threadIdx.x;
  const int w = t >> 6, l = t & 63;
  const int lane16 = l & 15, quad = l >> 4;

  __shared__ __align__(16) unsigned char smem[64768];
  hbf (*qgs)[136] = (hbf(*)[136])(smem);                 // 17408 B
  hbf (*Ald)[72]  = (hbf(*)[72]) (smem + 17408);         //  9216 B
  hbf (*kgs)[136] = (hbf(*)[136])(smem + 26624);         // 17408 B (phase 1)
  hbf (*vT)[72]   = (hbf(*)[72]) (smem + 26624);         // 36864 B (phase 2, aliases kgs)
  float* ssum     = (float*)     (smem + 63488);         // 64*4
  float* invb     = (float*)     (smem + 64512);         // 64

  const float scale = 0.088388347648318447f;  // 128^-0.5
  const int bc = b*TDIM + nc*CHUNKC;

  #pragma unroll
  for (int i = 0; i < 32; ++i) {
    int idx = t + 256*i;
    int c = idx >> 7, kk = idx & 127;
    float g = Gb[(size_t)(bc + c)*KD + h*DK + kk];
    float qv = __bfloat162float(qkbf[(size_t)(bc + c)*1024 + h*DK + kk]);
    float kv = __bfloat162float(qkbf[(size_t)(bc + c)*1024 + 512 + h*DK + kk]);
    qgs[c][kk] = __float2bfloat16(qv * expf(g) * scale);
    kgs[c][kk] = __float2bfloat16(kv * expf(-g));
  }
  __syncthreads();

  f32x4 acc1[4] = {};
  #pragma unroll
  for (int kc = 0; kc < 4; ++kc) {
    bf16x8 af = *(const bf16x8*)&qgs[w*16 + lane16][kc*32 + quad*8];
    #pragma unroll
    for (int j = 0; j < 4; ++j) {
      bf16x8 bf = *(const bf16x8*)&kgs[j*16 + lane16][kc*32 + quad*8];
      acc1[j] = __builtin_amdgcn_mfma_f32_16x16x32_bf16(af, bf, acc1[j], 0, 0, 0);
    }
  }
  __syncthreads();

  #pragma unroll
  for (int j = 0; j < 4; ++j)
    #pragma unroll
    for (int r = 0; r < 4; ++r) {
      int cr = w*16 + quad*4 + r;
      int cc = j*16 + lane16;
      Ald[cr][cc] = __float2bfloat16(cc <= cr ? acc1[j][r] : 0.f);
    }
  #pragma unroll
  for (int i = 0; i < 64; ++i) {
    int e = t + 256*i;
    int c = e >> 8, col = e & 255;
    vT[col][c] = vgbf[(size_t)(bc + c)*2048 + h*DV + col];
  }
  __syncthreads();

  const hbf* SpB = Spb + ((size_t)nc*8 + (b*HH + h))*((size_t)DK*DV);
  f32x4 acc[4][4] = {};
  #pragma unroll
  for (int kc = 0; kc < 4; ++kc) {
    bf16x8 af[4], bs[4];
    #pragma unroll
    for (int i = 0; i < 4; ++i)
      af[i] = *(const bf16x8*)&qgs[i*16 + lane16][kc*32 + quad*8];
    #pragma unroll
    for (int j = 0; j < 4; ++j) {
      int n = w*64 + j*16 + lane16;
      bs[j] = *(const bf16x8*)(SpB + (size_t)n*DK + kc*32 + quad*8);
    }
    #pragma unroll
    for (int i = 0; i < 4; ++i)
      #pragma unroll
      for (int j = 0; j < 4; ++j)
        acc[i][j] = __builtin_amdgcn_mfma_f32_16x16x32_bf16(af[i], bs[j], acc[i][j], 0, 0, 0);
  }
  #pragma unroll
  for (int kc = 0; kc < 2; ++kc) {
    bf16x8 aa[4], bv[4];
    #pragma unroll
    for (int i = 0; i < 4; ++i)
      aa[i] = *(const bf16x8*)&Ald[i*16 + lane16][kc*32 + quad*8];
    #pragma unroll
    for (int j = 0; j < 4; ++j)
      bv[j] = *(const bf16x8*)&vT[w*64 + j*16 + lane16][kc*32 + quad*8];
    #pragma unroll
    for (int i = 0; i < 4; ++i)
      #pragma unroll
      for (int j = 0; j < 4; ++j)
        acc[i][j] = __builtin_amdgcn_mfma_f32_16x16x32_bf16(aa[i], bv[j], acc[i][j], 0, 0, 0);
  }

  #pragma unroll
  for (int i = 0; i < 4; ++i)
    #pragma unroll
    for (int r = 0; r < 4; ++r) {
      float s = 0.f;
      #pragma unroll
      for (int j = 0; j < 4; ++j) s += acc[i][j][r]*acc[i][j][r];
      s += __shfl_xor(s, 1); s += __shfl_xor(s, 2);
      s += __shfl_xor(s, 4); s += __shfl_xor(s, 8);
      if (lane16 == 0) ssum[(i*16 + quad*4 + r)*4 + w] = s;
    }
  __syncthreads();
  if (t < 64) {
    float tot = ssum[t*4] + ssum[t*4+1] + ssum[t*4+2] + ssum[t*4+3];
    invb[t] = rsqrtf(tot * (1.0f/DV) + 1e-6f);
  }
  __syncthreads();
  float gnwv[4];
  #pragma unroll
  for (int j = 0; j < 4; ++j) gnwv[j] = gnw[w*64 + j*16 + lane16];
  #pragma unroll
  for (int i = 0; i < 4; ++i)
    #pragma unroll
    for (int r = 0; r < 4; ++r) {
      int m = i*16 + quad*4 + r;
      float inv = invb[m];
      size_t grow_ = (size_t)(bc + m)*2048 + 1024 + h*DV + w*64;
      size_t orow_ = (size_t)(bc + m)*VD + h*DV + w*64;
      #pragma unroll
      for (int j = 0; j < 4; ++j) {
        float gv = __bfloat162float(vgbf[grow_ + j*16 + lane16]);
        float sig = 1.f / (1.f + expf(-gv));
        float val = acc[i][j][r] * inv * gnwv[j];
        obf[orow_ + j*16 + lane16] = __float2bfloat16(val * (gv * sig));
      }
    }
}

extern "C" void kernel_launch(void* const* d_in, const int* in_sizes, int n_in,
                              void* d_out, int out_size, void* d_ws, size_t ws_size,
                              hipStream_t stream) {
  const float* x    = (const float*)d_in[0];
  const float* Wq   = (const float*)d_in[1];
  const float* Wk   = (const float*)d_in[2];
  const float* Wv   = (const float*)d_in[3];
  const float* Wg   = (const float*)d_in[4];
  const float* Wgk1 = (const float*)d_in[5];
  const float* Wgk2 = (const float*)d_in[6];
  const float* bgk2 = (const float*)d_in[7];
  const float* gnw  = (const float*)d_in[8];
  const float* Wo   = (const float*)d_in[9];
  float* out = (float*)d_out;

  float* ws  = (float*)d_ws;
  float* Gb  = ws;                                   // 4096*512 fp32 (gk pre -> G)
  float* dec = Gb  + (size_t)MTOT*KD;                // 32*8*128 fp32
  hbf* xbf   = (hbf*)(dec + (size_t)NC*BDIM*HH*DK);  // 4096*1024 bf16
  hbf* wtall = xbf   + (size_t)MTOT*DDIM;            // 3584*1024 bf16 (Wq|Wk|Wc|Wv|Wg)^T
  hbf* wto   = wtall + (size_t)NALL*DDIM;            // 1024*1024 bf16
  hbf* qkbf  = wto   + (size_t)DDIM*DDIM;            // 4096*1024 bf16 (q|k)
  hbf* vgbf  = qkbf  + (size_t)MTOT*1024;            // 4096*2048 bf16 (v|g)
  hbf* Ub    = vgbf  + (size_t)MTOT*2048;            // 32*262144 bf16 (U, [v][k])
  hbf* Spb   = Ub    + (size_t)NC*STRIDE_ST;         // 32*262144 bf16 (S_prev, [v][k])
  hbf* obf   = Ub;                                   // alias: U dead before out_kernel

  cast_bf16_kernel<<<MTOT*DDIM/4/256, 256, 0, stream>>>(x, xbf);
  prep_weights<<<dim3(144, 32), 256, 0, stream>>>(Wq, Wk, Wv, Wg, Wo, Wgk1, Wgk2, wtall, wto);

  gemm_proj<<<dim3(NALL/256, MTOT/128), 256, 0, stream>>>(xbf, wtall, Gb, qkbf, vgbf);

  gkcumsum_kernel<<<256, 256, 0, stream>>>(Gb, bgk2);
  state_chunk_kernel<<<NC*BDIM*HH, 256, 0, stream>>>(qkbf, vgbf, Gb, Ub, dec);
  state_scan_kernel<<<(int)(STRIDE_ST/2/256), 256, 0, stream>>>(Ub, dec, Spb);
  out_kernel<<<NC*BDIM*HH, 256, 0, stream>>>(qkbf, vgbf, Gb, Spb, gnw, obf);
  gemm_bt<<<dim3(DDIM/128, MTOT/128), 256, 0, stream>>>(obf, wto, out, MTOT, DDIM, DDIM);
}

// Round 10
// 231.006 us; speedup vs baseline: 1.1216x; 1.1216x over previous
//
#include <hip/hip_runtime.h>
#include <hip/hip_bf16.h>

#define BDIM 2
#define TDIM 2048
#define DDIM 1024
#define HH 4
#define KD 512
#define VD 1024
#define DK 128
#define DV 256
#define NC 32
#define CHUNKC 64
#define MTOT (BDIM*TDIM)   // 4096
#define NALL 3584          // q|k (1024) | gk (512) | v|g (2048)
#define STRIDE_ST ((size_t)BDIM*HH*DK*DV)   // 262144 elems per chunk of states

typedef __bf16 bf16x8 __attribute__((ext_vector_type(8)));
typedef float  f32x4  __attribute__((ext_vector_type(4)));
typedef __hip_bfloat16 hbf;

__device__ __forceinline__ void async_copy16(const void* g, void* l) {
  __builtin_amdgcn_global_load_lds(
      (const __attribute__((address_space(1))) void*)g,
      (__attribute__((address_space(3))) void*)l, 16, 0, 0);
}

// ---------------- cast x (fp32 -> bf16), 4 elems/thread ----------------
__global__ void cast_bf16_kernel(const float* __restrict__ src, hbf* __restrict__ dst) {
  int t = blockIdx.x*256 + threadIdx.x;
  float4 v = ((const float4*)src)[t];
  union { hbf h[4]; uint2 u; } o;
  o.h[0] = __float2bfloat16(v.x); o.h[1] = __float2bfloat16(v.y);
  o.h[2] = __float2bfloat16(v.z); o.h[3] = __float2bfloat16(v.w);
  ((uint2*)dst)[t] = o.u;
}

// ---------------- one-shot weight prep: transpose+cast all W, compute Wc^T ----
__global__ void prep_weights(const float* __restrict__ Wq, const float* __restrict__ Wk,
                             const float* __restrict__ Wv, const float* __restrict__ Wg,
                             const float* __restrict__ Wo, const float* __restrict__ W1,
                             const float* __restrict__ W2,
                             hbf* __restrict__ wtall, hbf* __restrict__ wto) {
  __shared__ float tile[32][33];
  const int n0 = blockIdx.x*32, k0 = blockIdx.y*32;
  const int tx = threadIdx.x & 31, ty = threadIdx.x >> 5;
  if (n0 >= 1024 && n0 < 1536) {          // Wc = (Wgk1 @ Wgk2)^T
    #pragma unroll
    for (int r = ty; r < 32; r += 8) {
      int n = n0 - 1024 + r, k = k0 + tx;
      float s = 0.f;
      #pragma unroll
      for (int j = 0; j < 16; ++j) s += W1[(size_t)k*16 + j] * W2[(size_t)j*KD + n];
      wtall[(size_t)(n0 + r)*DDIM + k] = __float2bfloat16(s);
    }
    return;
  }
  const float* W; int Nsrc, nloc; hbf* outp; int orow;
  if      (n0 < 512)  { W = Wq; Nsrc = 512;  nloc = n0;        outp = wtall; orow = n0; }
  else if (n0 < 1024) { W = Wk; Nsrc = 512;  nloc = n0 - 512;  outp = wtall; orow = n0; }
  else if (n0 < 2560) { W = Wv; Nsrc = 1024; nloc = n0 - 1536; outp = wtall; orow = n0; }
  else if (n0 < 3584) { W = Wg; Nsrc = 1024; nloc = n0 - 2560; outp = wtall; orow = n0; }
  else                { W = Wo; Nsrc = 1024; nloc = n0 - 3584; outp = wto;   orow = n0 - 3584; }
  #pragma unroll
  for (int r = ty; r < 32; r += 8)
    tile[r][tx] = W[(size_t)(k0 + r)*Nsrc + nloc + tx];
  __syncthreads();
  #pragma unroll
  for (int r = ty; r < 32; r += 8)
    outp[(size_t)(orow + r)*DDIM + k0 + tx] = __float2bfloat16(tile[tx][r]);
}

// ---------------- MFMA GEMM, 128x128, BK=64, swizzled LDS ----------------
// MODE 0: fp32 C[M,N].   MODE 1: mixed epilogue (qk bf16 | G fp32 | vg bf16).
template <int MODE>
__global__ __launch_bounds__(256) void gemm_bt(const hbf* __restrict__ A,
                                               const hbf* __restrict__ Bt,
                                               float* __restrict__ Cf,
                                               hbf* __restrict__ Cq,
                                               hbf* __restrict__ Cv,
                                               int M, int N, int K) {
  __shared__ hbf As0[128][32], As1[128][32];
  __shared__ hbf Bs0[128][32], Bs1[128][32];
  const int t = threadIdx.x;
  const int w = t >> 6, l = t & 63;
  const int lr = l >> 2;
  const int srcc = (((l & 3) - (l >> 4)) & 3) * 8;   // swizzled source chunk
  const int lane16 = l & 15, quad = l >> 4;
  const int sw = (lane16 >> 2) & 3;                   // row-dependent rotation
  const int row0 = blockIdx.y*128, col0 = blockIdx.x*128;
  const int mb = (w >> 1)*64, nb = (w & 1)*64;

  const hbf* ga = A  + (size_t)(row0 + w*32 + lr)*K + srcc;
  const hbf* gb = Bt + (size_t)(col0 + w*32 + lr)*K + srcc;
  hbf* la0 = &As0[w*32][0];   hbf* la1 = &As0[w*32 + 16][0];
  hbf* la2 = &As1[w*32][0];   hbf* la3 = &As1[w*32 + 16][0];
  hbf* lb0 = &Bs0[w*32][0];   hbf* lb1 = &Bs0[w*32 + 16][0];
  hbf* lb2 = &Bs1[w*32][0];   hbf* lb3 = &Bs1[w*32 + 16][0];
  const size_t rstep = (size_t)16*K;

  f32x4 acc[4][4] = {};
  for (int k0 = 0; k0 < K; k0 += 64) {
    async_copy16(ga,              la0);
    async_copy16(ga + rstep,      la1);
    async_copy16(ga + 32,         la2);
    async_copy16(ga + rstep + 32, la3);
    async_copy16(gb,              lb0);
    async_copy16(gb + rstep,      lb1);
    async_copy16(gb + 32,         lb2);
    async_copy16(gb + rstep + 32, lb3);
    ga += 64; gb += 64;
    __syncthreads();
    {
      bf16x8 af[4], bfr[4];
      #pragma unroll
      for (int i = 0; i < 4; ++i)
        af[i] = *(const bf16x8*)&As0[mb + i*16 + lane16][((quad + sw) & 3)*8];
      #pragma unroll
      for (int j = 0; j < 4; ++j)
        bfr[j] = *(const bf16x8*)&Bs0[nb + j*16 + lane16][((quad + sw) & 3)*8];
      #pragma unroll
      for (int i = 0; i < 4; ++i)
        #pragma unroll
        for (int j = 0; j < 4; ++j)
          acc[i][j] = __builtin_amdgcn_mfma_f32_16x16x32_bf16(af[i], bfr[j], acc[i][j], 0, 0, 0);
    }
    {
      bf16x8 af[4], bfr[4];
      #pragma unroll
      for (int i = 0; i < 4; ++i)
        af[i] = *(const bf16x8*)&As1[mb + i*16 + lane16][((quad + sw) & 3)*8];
      #pragma unroll
      for (int j = 0; j < 4; ++j)
        bfr[j] = *(const bf16x8*)&Bs1[nb + j*16 + lane16][((quad + sw) & 3)*8];
      #pragma unroll
      for (int i = 0; i < 4; ++i)
        #pragma unroll
        for (int j = 0; j < 4; ++j)
          acc[i][j] = __builtin_amdgcn_mfma_f32_16x16x32_bf16(af[i], bfr[j], acc[i][j], 0, 0, 0);
    }
    __syncthreads();
  }
  #pragma unroll
  for (int i = 0; i < 4; ++i)
    #pragma unroll
    for (int j = 0; j < 4; ++j)
      #pragma unroll
      for (int r = 0; r < 4; ++r) {
        int m = row0 + mb + i*16 + quad*4 + r;
        int n = col0 + nb + j*16 + lane16;
        float v = acc[i][j][r];
        if (MODE == 0) {
          Cf[(size_t)m*N + n] = v;
        } else {
          if (n < 1024)       Cq[(size_t)m*1024 + n] = __float2bfloat16(v);
          else if (n < 1536)  Cf[(size_t)m*512  + n - 1024] = v;
          else                Cv[(size_t)m*2048 + n - 1536] = __float2bfloat16(v);
        }
      }
}

// ---------------- gate: G=cumsum(logsig(pre+b)/16); emit qg, kg, kbar bf16 + dec ----
// grid: 256 = b*128 + nc*4 + h  (the 128-col slice IS head h)
__global__ __launch_bounds__(256) void gate_kernel(const float* __restrict__ Gpre,
                                                   const hbf* __restrict__ qkbf,
                                                   const float* __restrict__ bias,
                                                   hbf* __restrict__ qgb,
                                                   hbf* __restrict__ kgb,
                                                   hbf* __restrict__ kbarb,
                                                   float* __restrict__ dec) {
  __shared__ float buf[CHUNKC][128];
  const int h  = blockIdx.x & 3;
  const int nc = (blockIdx.x >> 2) & 31;
  const int b  = blockIdx.x >> 7;
  const int t = threadIdx.x;
  const int bc = b*TDIM + nc*CHUNKC;
  const int col0 = h*128;
  #pragma unroll
  for (int i = 0; i < 32; ++i) {
    int idx = t + 256*i;
    int c = idx >> 7, col = idx & 127;
    float s = Gpre[(size_t)(bc + c)*KD + col0 + col] + bias[col0 + col];
    buf[c][col] = (fminf(s, 0.f) - log1pf(expf(-fabsf(s)))) * (1.0f/16.0f);
  }
  __syncthreads();
  if (t < 128) {
    float acc = 0.f;
    #pragma unroll
    for (int c = 0; c < CHUNKC; ++c) { acc += buf[c][t]; buf[c][t] = acc; }
    dec[((size_t)nc*8 + b*HH + h)*DK + t] = expf(acc);
  }
  __syncthreads();
  const float scale = 0.088388347648318447f;  // 128^-0.5
  #pragma unroll
  for (int i = 0; i < 16; ++i) {
    int idx = t + 256*i;                 // 4096 col-pairs
    int c = idx >> 6, cp = (idx & 63)*2;
    float g0 = buf[c][cp], g1 = buf[c][cp + 1];
    float gl0 = buf[63][cp], gl1 = buf[63][cp + 1];
    const size_t qoff = (size_t)(bc + c)*1024 + col0 + cp;
    uint qu = *(const uint*)(qkbf + qoff);
    uint ku = *(const uint*)(qkbf + qoff + 512);
    float q0 = __bfloat162float(((const hbf*)&qu)[0]);
    float q1 = __bfloat162float(((const hbf*)&qu)[1]);
    float k0 = __bfloat162float(((const hbf*)&ku)[0]);
    float k1 = __bfloat162float(((const hbf*)&ku)[1]);
    union { hbf h2[2]; uint u; } o1, o2, o3;
    o1.h2[0] = __float2bfloat16(q0 * expf(g0) * scale);
    o1.h2[1] = __float2bfloat16(q1 * expf(g1) * scale);
    o2.h2[0] = __float2bfloat16(k0 * expf(-g0));
    o2.h2[1] = __float2bfloat16(k1 * expf(-g1));
    o3.h2[0] = __float2bfloat16(k0 * expf(gl0 - g0));
    o3.h2[1] = __float2bfloat16(k1 * expf(gl1 - g1));
    const size_t ooff = (size_t)(bc + c)*KD + col0 + cp;
    *(uint*)(qgb + ooff)   = o1.u;
    *(uint*)(kgb + ooff)   = o2.u;
    *(uint*)(kbarb + ooff) = o3.u;
  }
}

// ---------------- per-chunk state increment (MFMA): U[v][k] bf16 ----------------
__global__ __launch_bounds__(256) void state_chunk_kernel(const hbf* __restrict__ kbarb,
                                                          const hbf* __restrict__ vgbf,
                                                          hbf* __restrict__ Ub) {
  const int bh = blockIdx.x & 7;
  const int nc = blockIdx.x >> 3;
  const int b = bh >> 2, h = bh & 3;
  const int t = threadIdx.x;
  const int w = t >> 6, l = t & 63;
  const int lane16 = l & 15, quad = l >> 4;
  __shared__ hbf kbarT[DK][72];     // [k][c]
  __shared__ hbf vT[DV][72];        // [v][c]
  const int bc = b*TDIM + nc*CHUNKC;
  #pragma unroll
  for (int i = 0; i < 32; ++i) {
    int idx = t + 256*i;
    int c = idx >> 7, kk = idx & 127;
    kbarT[kk][c] = kbarb[(size_t)(bc + c)*KD + h*DK + kk];
  }
  #pragma unroll
  for (int i = 0; i < 64; ++i) {
    int idx = t + 256*i;
    int c = idx >> 8, col = idx & 255;
    vT[col][c] = vgbf[(size_t)(bc + c)*2048 + h*DV + col];
  }
  __syncthreads();
  f32x4 acc[4][8] = {};
  #pragma unroll
  for (int kc = 0; kc < 2; ++kc) {
    bf16x8 av[4], bk[8];
    #pragma unroll
    for (int i = 0; i < 4; ++i)
      av[i] = *(const bf16x8*)&vT[w*64 + i*16 + lane16][kc*32 + quad*8];
    #pragma unroll
    for (int j = 0; j < 8; ++j)
      bk[j] = *(const bf16x8*)&kbarT[j*16 + lane16][kc*32 + quad*8];
    #pragma unroll
    for (int i = 0; i < 4; ++i)
      #pragma unroll
      for (int j = 0; j < 8; ++j)
        acc[i][j] = __builtin_amdgcn_mfma_f32_16x16x32_bf16(av[i], bk[j], acc[i][j], 0, 0, 0);
  }
  hbf* ub = Ub + ((size_t)nc*8 + bh)*((size_t)DK*DV);
  #pragma unroll
  for (int i = 0; i < 4; ++i)
    #pragma unroll
    for (int j = 0; j < 8; ++j)
      #pragma unroll
      for (int r = 0; r < 4; ++r) {
        int v = w*64 + i*16 + quad*4 + r;
        int k = j*16 + lane16;
        ub[(size_t)v*DK + k] = __float2bfloat16(acc[i][j][r]);
      }
}

// ---------------- scan over chunks: reads U bf16, fp32 accum, writes S_prev bf16 ----
__global__ __launch_bounds__(256) void state_scan_kernel(const hbf* __restrict__ Ub,
                                                         const float* __restrict__ dec,
                                                         hbf* __restrict__ Spb) {
  const int p = blockIdx.x*256 + threadIdx.x;   // pair index 0..131071
  const size_t e = (size_t)p*2;
  const int k = (int)(e & 127);
  const int bh = (int)(e >> 15);
  float S0 = 0.f, S1 = 0.f;
  for (int nc = 0; nc < NC; ++nc) {
    const size_t off = (size_t)nc*STRIDE_ST + e;
    uint uu = *(const uint*)(Ub + off);
    hbf u0 = *(const hbf*)&uu;
    hbf u1 = *((const hbf*)&uu + 1);
    union { hbf h[2]; uint u; } ov;
    ov.h[0] = __float2bfloat16(S0); ov.h[1] = __float2bfloat16(S1);
    *(uint*)(Spb + off) = ov.u;
    float2 d = *(const float2*)(dec + ((size_t)nc*8 + bh)*DK + k);
    S0 = S0 * d.x + __bfloat162float(u0);
    S1 = S1 * d.y + __bfloat162float(u1);
  }
}

// ---------------- per-chunk output (MFMA): tril(qg kg^T), qg@S + A@v, RMSNorm, gate ----
__global__ __launch_bounds__(256) void out_kernel(const hbf* __restrict__ qgb,
                                                  const hbf* __restrict__ kgb,
                                                  const hbf* __restrict__ vgbf,
                                                  const hbf* __restrict__ Spb,
                                                  const float* __restrict__ gnw,
                                                  hbf* __restrict__ obf) {
  const int blk = blockIdx.x;
  const int h = blk & 3, b = (blk >> 2) & 1, nc = blk >> 3;
  const int t = threadIdx.x;
  const int w = t >> 6, l = t & 63;
  const int lane16 = l & 15, quad = l >> 4;

  __shared__ __align__(16) unsigned char smem[64768];
  hbf (*qgs)[136] = (hbf(*)[136])(smem);                 // 17408 B
  hbf (*Ald)[72]  = (hbf(*)[72]) (smem + 17408);         //  9216 B
  hbf (*kgs)[136] = (hbf(*)[136])(smem + 26624);         // 17408 B (phase 1)
  hbf (*vT)[72]   = (hbf(*)[72]) (smem + 26624);         // 36864 B (phase 2, aliases kgs)
  float* ssum     = (float*)     (smem + 63488);         // 64*4
  float* invb     = (float*)     (smem + 64512);         // 64

  const int bc = b*TDIM + nc*CHUNKC;

  // ---- stage qg, kg (vectorized 16B copies) ----
  #pragma unroll
  for (int i = 0; i < 4; ++i) {
    int idx = t + 256*i;                 // 1024 chunks of 8 elems
    int c = idx >> 4, ch = (idx & 15)*8;
    *(uint4*)&qgs[c][ch] = *(const uint4*)(qgb + (size_t)(bc + c)*KD + h*DK + ch);
    *(uint4*)&kgs[c][ch] = *(const uint4*)(kgb + (size_t)(bc + c)*KD + h*DK + ch);
  }
  __syncthreads();

  f32x4 acc1[4] = {};
  #pragma unroll
  for (int kc = 0; kc < 4; ++kc) {
    bf16x8 af = *(const bf16x8*)&qgs[w*16 + lane16][kc*32 + quad*8];
    #pragma unroll
    for (int j = 0; j < 4; ++j) {
      bf16x8 bf = *(const bf16x8*)&kgs[j*16 + lane16][kc*32 + quad*8];
      acc1[j] = __builtin_amdgcn_mfma_f32_16x16x32_bf16(af, bf, acc1[j], 0, 0, 0);
    }
  }
  __syncthreads();

  #pragma unroll
  for (int j = 0; j < 4; ++j)
    #pragma unroll
    for (int r = 0; r < 4; ++r) {
      int cr = w*16 + quad*4 + r;
      int cc = j*16 + lane16;
      Ald[cr][cc] = __float2bfloat16(cc <= cr ? acc1[j][r] : 0.f);
    }
  #pragma unroll
  for (int i = 0; i < 64; ++i) {
    int e = t + 256*i;
    int c = e >> 8, col = e & 255;
    vT[col][c] = vgbf[(size_t)(bc + c)*2048 + h*DV + col];
  }
  __syncthreads();

  const hbf* SpB = Spb + ((size_t)nc*8 + (b*HH + h))*((size_t)DK*DV);
  f32x4 acc[4][4] = {};
  #pragma unroll
  for (int kc = 0; kc < 4; ++kc) {
    bf16x8 af[4], bs[4];
    #pragma unroll
    for (int i = 0; i < 4; ++i)
      af[i] = *(const bf16x8*)&qgs[i*16 + lane16][kc*32 + quad*8];
    #pragma unroll
    for (int j = 0; j < 4; ++j) {
      int n = w*64 + j*16 + lane16;
      bs[j] = *(const bf16x8*)(SpB + (size_t)n*DK + kc*32 + quad*8);
    }
    #pragma unroll
    for (int i = 0; i < 4; ++i)
      #pragma unroll
      for (int j = 0; j < 4; ++j)
        acc[i][j] = __builtin_amdgcn_mfma_f32_16x16x32_bf16(af[i], bs[j], acc[i][j], 0, 0, 0);
  }
  #pragma unroll
  for (int kc = 0; kc < 2; ++kc) {
    bf16x8 aa[4], bv[4];
    #pragma unroll
    for (int i = 0; i < 4; ++i)
      aa[i] = *(const bf16x8*)&Ald[i*16 + lane16][kc*32 + quad*8];
    #pragma unroll
    for (int j = 0; j < 4; ++j)
      bv[j] = *(const bf16x8*)&vT[w*64 + j*16 + lane16][kc*32 + quad*8];
    #pragma unroll
    for (int i = 0; i < 4; ++i)
      #pragma unroll
      for (int j = 0; j < 4; ++j)
        acc[i][j] = __builtin_amdgcn_mfma_f32_16x16x32_bf16(aa[i], bv[j], acc[i][j], 0, 0, 0);
  }

  #pragma unroll
  for (int i = 0; i < 4; ++i)
    #pragma unroll
    for (int r = 0; r < 4; ++r) {
      float s = 0.f;
      #pragma unroll
      for (int j = 0; j < 4; ++j) s += acc[i][j][r]*acc[i][j][r];
      s += __shfl_xor(s, 1); s += __shfl_xor(s, 2);
      s += __shfl_xor(s, 4); s += __shfl_xor(s, 8);
      if (lane16 == 0) ssum[(i*16 + quad*4 + r)*4 + w] = s;
    }
  __syncthreads();
  if (t < 64) {
    float tot = ssum[t*4] + ssum[t*4+1] + ssum[t*4+2] + ssum[t*4+3];
    invb[t] = rsqrtf(tot * (1.0f/DV) + 1e-6f);
  }
  __syncthreads();
  float gnwv[4];
  #pragma unroll
  for (int j = 0; j < 4; ++j) gnwv[j] = gnw[w*64 + j*16 + lane16];
  #pragma unroll
  for (int i = 0; i < 4; ++i)
    #pragma unroll
    for (int r = 0; r < 4; ++r) {
      int m = i*16 + quad*4 + r;
      float inv = invb[m];
      size_t grow_ = (size_t)(bc + m)*2048 + 1024 + h*DV + w*64;
      size_t orow_ = (size_t)(bc + m)*VD + h*DV + w*64;
      #pragma unroll
      for (int j = 0; j < 4; ++j) {
        float gv = __bfloat162float(vgbf[grow_ + j*16 + lane16]);
        float sig = 1.f / (1.f + expf(-gv));
        float val = acc[i][j][r] * inv * gnwv[j];
        obf[orow_ + j*16 + lane16] = __float2bfloat16(val * (gv * sig));
      }
    }
}

extern "C" void kernel_launch(void* const* d_in, const int* in_sizes, int n_in,
                              void* d_out, int out_size, void* d_ws, size_t ws_size,
                              hipStream_t stream) {
  const float* x    = (const float*)d_in[0];
  const float* Wq   = (const float*)d_in[1];
  const float* Wk   = (const float*)d_in[2];
  const float* Wv   = (const float*)d_in[3];
  const float* Wg   = (const float*)d_in[4];
  const float* Wgk1 = (const float*)d_in[5];
  const float* Wgk2 = (const float*)d_in[6];
  const float* bgk2 = (const float*)d_in[7];
  const float* gnw  = (const float*)d_in[8];
  const float* Wo   = (const float*)d_in[9];
  float* out = (float*)d_out;

  float* ws  = (float*)d_ws;
  float* Gb  = ws;                                   // 4096*512 fp32 (gk preact)
  float* dec = Gb  + (size_t)MTOT*KD;                // 32*8*128 fp32
  hbf* xbf   = (hbf*)(dec + (size_t)NC*BDIM*HH*DK);  // 4096*1024 bf16
  hbf* wtall = xbf   + (size_t)MTOT*DDIM;            // 3584*1024 bf16
  hbf* wto   = wtall + (size_t)NALL*DDIM;            // 1024*1024 bf16
  hbf* qkbf  = wto   + (size_t)DDIM*DDIM;            // 4096*1024 bf16 (q|k)
  hbf* vgbf  = qkbf  + (size_t)MTOT*1024;            // 4096*2048 bf16 (v|g)
  hbf* qgb   = vgbf  + (size_t)MTOT*2048;            // 4096*512 bf16
  hbf* kgb   = qgb   + (size_t)MTOT*KD;              // 4096*512 bf16
  hbf* kbarb = kgb   + (size_t)MTOT*KD;              // 4096*512 bf16
  hbf* Ub    = kbarb + (size_t)MTOT*KD;              // 32*262144 bf16 (U, [v][k])
  hbf* Spb   = Ub    + (size_t)NC*STRIDE_ST;         // 32*262144 bf16 (S_prev, [v][k])
  hbf* obf   = Ub;                                   // alias: U dead before out_kernel

  cast_bf16_kernel<<<MTOT*DDIM/4/256, 256, 0, stream>>>(x, xbf);
  prep_weights<<<dim3(144, 32), 256, 0, stream>>>(Wq, Wk, Wv, Wg, Wo, Wgk1, Wgk2, wtall, wto);

  gemm_bt<1><<<dim3(NALL/128, MTOT/128), 256, 0, stream>>>(xbf, wtall, Gb, qkbf, vgbf, MTOT, NALL, DDIM);

  gate_kernel<<<256, 256, 0, stream>>>(Gb, qkbf, bgk2, qgb, kgb, kbarb, dec);
  state_chunk_kernel<<<NC*BDIM*HH, 256, 0, stream>>>(kbarb, vgbf, Ub);
  state_scan_kernel<<<(int)(STRIDE_ST/2/256), 256, 0, stream>>>(Ub, dec, Spb);
  out_kernel<<<NC*BDIM*HH, 256, 0, stream>>>(qgb, kgb, vgbf, Spb, gnw, obf);
  gemm_bt<0><<<dim3(DDIM/128, MTOT/128), 256, 0, stream>>>(obf, wto, out, (hbf*)nullptr, (hbf*)nullptr, MTOT, DDIM, DDIM);
}

// Round 11
// 219.539 us; speedup vs baseline: 1.1801x; 1.0522x over previous
//
#include <hip/hip_runtime.h>
#include <hip/hip_bf16.h>

#define BDIM 2
#define TDIM 2048
#define DDIM 1024
#define HH 4
#define KD 512
#define VD 1024
#define DK 128
#define DV 256
#define NC 32
#define CHUNKC 64
#define MTOT (BDIM*TDIM)   // 4096
#define NALL 3584          // q|k (1024) | gk (512) | v|g (2048)
#define STRIDE_ST ((size_t)BDIM*HH*DK*DV)   // 262144 elems per chunk of states

typedef __bf16 bf16x8 __attribute__((ext_vector_type(8)));
typedef float  f32x4  __attribute__((ext_vector_type(4)));
typedef __hip_bfloat16 hbf;

__device__ __forceinline__ void async_copy16(const void* g, void* l) {
  __builtin_amdgcn_global_load_lds(
      (const __attribute__((address_space(1))) void*)g,
      (__attribute__((address_space(3))) void*)l, 16, 0, 0);
}

// ---------------- fused prep: x cast (blocks 0..4095) + weight transpose/cast ----
__global__ void fused_prep(const float* __restrict__ x, hbf* __restrict__ xbf,
                           const float* __restrict__ Wq, const float* __restrict__ Wk,
                           const float* __restrict__ Wv, const float* __restrict__ Wg,
                           const float* __restrict__ Wo, const float* __restrict__ W1,
                           const float* __restrict__ W2,
                           hbf* __restrict__ wtall, hbf* __restrict__ wto) {
  __shared__ float tile[32][33];
  if (blockIdx.x < 4096) {            // cast path: 4 elems/thread
    int t = blockIdx.x*256 + threadIdx.x;
    float4 v = ((const float4*)x)[t];
    union { hbf h[4]; uint2 u; } o;
    o.h[0] = __float2bfloat16(v.x); o.h[1] = __float2bfloat16(v.y);
    o.h[2] = __float2bfloat16(v.z); o.h[3] = __float2bfloat16(v.w);
    ((uint2*)xbf)[t] = o.u;
    return;
  }
  const int bb = blockIdx.x - 4096;   // 4608 prep blocks
  const int n0 = (bb % 144)*32, k0 = (bb / 144)*32;
  const int tx = threadIdx.x & 31, ty = threadIdx.x >> 5;
  if (n0 >= 1024 && n0 < 1536) {      // Wc = (Wgk1 @ Wgk2)^T
    #pragma unroll
    for (int r = ty; r < 32; r += 8) {
      int n = n0 - 1024 + r, k = k0 + tx;
      float s = 0.f;
      #pragma unroll
      for (int j = 0; j < 16; ++j) s += W1[(size_t)k*16 + j] * W2[(size_t)j*KD + n];
      wtall[(size_t)(n0 + r)*DDIM + k] = __float2bfloat16(s);
    }
    return;
  }
  const float* W; int Nsrc, nloc; hbf* outp; int orow;
  if      (n0 < 512)  { W = Wq; Nsrc = 512;  nloc = n0;        outp = wtall; orow = n0; }
  else if (n0 < 1024) { W = Wk; Nsrc = 512;  nloc = n0 - 512;  outp = wtall; orow = n0; }
  else if (n0 < 2560) { W = Wv; Nsrc = 1024; nloc = n0 - 1536; outp = wtall; orow = n0; }
  else if (n0 < 3584) { W = Wg; Nsrc = 1024; nloc = n0 - 2560; outp = wtall; orow = n0; }
  else                { W = Wo; Nsrc = 1024; nloc = n0 - 3584; outp = wto;   orow = n0 - 3584; }
  #pragma unroll
  for (int r = ty; r < 32; r += 8)
    tile[r][tx] = W[(size_t)(k0 + r)*Nsrc + nloc + tx];
  __syncthreads();
  #pragma unroll
  for (int r = ty; r < 32; r += 8)
    outp[(size_t)(orow + r)*DDIM + k0 + tx] = __float2bfloat16(tile[tx][r]);
}

// ---------------- MFMA GEMM, 128x128, BK=64 ----------------
// MODE 0: fp32 C[M,N].   MODE 1: mixed epilogue (qk bf16 | G fp32 | vg bf16).
template <int MODE>
__global__ __launch_bounds__(256) void gemm_bt(const hbf* __restrict__ A,
                                               const hbf* __restrict__ Bt,
                                               float* __restrict__ Cf,
                                               hbf* __restrict__ Cq,
                                               hbf* __restrict__ Cv,
                                               int M, int N, int K) {
  __shared__ hbf As0[128][32], As1[128][32];
  __shared__ hbf Bs0[128][32], Bs1[128][32];
  const int t = threadIdx.x;
  const int w = t >> 6, l = t & 63;
  const int lr = l >> 2;
  const int srcc = (((l & 3) - (l >> 4)) & 3) * 8;
  const int lane16 = l & 15, quad = l >> 4;
  const int sw = (lane16 >> 2) & 3;
  const int row0 = blockIdx.y*128, col0 = blockIdx.x*128;
  const int mb = (w >> 1)*64, nb = (w & 1)*64;

  const hbf* ga = A  + (size_t)(row0 + w*32 + lr)*K + srcc;
  const hbf* gb = Bt + (size_t)(col0 + w*32 + lr)*K + srcc;
  hbf* la0 = &As0[w*32][0];   hbf* la1 = &As0[w*32 + 16][0];
  hbf* la2 = &As1[w*32][0];   hbf* la3 = &As1[w*32 + 16][0];
  hbf* lb0 = &Bs0[w*32][0];   hbf* lb1 = &Bs0[w*32 + 16][0];
  hbf* lb2 = &Bs1[w*32][0];   hbf* lb3 = &Bs1[w*32 + 16][0];
  const size_t rstep = (size_t)16*K;

  f32x4 acc[4][4] = {};
  for (int k0 = 0; k0 < K; k0 += 64) {
    async_copy16(ga,              la0);
    async_copy16(ga + rstep,      la1);
    async_copy16(ga + 32,         la2);
    async_copy16(ga + rstep + 32, la3);
    async_copy16(gb,              lb0);
    async_copy16(gb + rstep,      lb1);
    async_copy16(gb + 32,         lb2);
    async_copy16(gb + rstep + 32, lb3);
    ga += 64; gb += 64;
    __syncthreads();
    {
      bf16x8 af[4], bfr[4];
      #pragma unroll
      for (int i = 0; i < 4; ++i)
        af[i] = *(const bf16x8*)&As0[mb + i*16 + lane16][((quad + sw) & 3)*8];
      #pragma unroll
      for (int j = 0; j < 4; ++j)
        bfr[j] = *(const bf16x8*)&Bs0[nb + j*16 + lane16][((quad + sw) & 3)*8];
      #pragma unroll
      for (int i = 0; i < 4; ++i)
        #pragma unroll
        for (int j = 0; j < 4; ++j)
          acc[i][j] = __builtin_amdgcn_mfma_f32_16x16x32_bf16(af[i], bfr[j], acc[i][j], 0, 0, 0);
    }
    {
      bf16x8 af[4], bfr[4];
      #pragma unroll
      for (int i = 0; i < 4; ++i)
        af[i] = *(const bf16x8*)&As1[mb + i*16 + lane16][((quad + sw) & 3)*8];
      #pragma unroll
      for (int j = 0; j < 4; ++j)
        bfr[j] = *(const bf16x8*)&Bs1[nb + j*16 + lane16][((quad + sw) & 3)*8];
      #pragma unroll
      for (int i = 0; i < 4; ++i)
        #pragma unroll
        for (int j = 0; j < 4; ++j)
          acc[i][j] = __builtin_amdgcn_mfma_f32_16x16x32_bf16(af[i], bfr[j], acc[i][j], 0, 0, 0);
    }
    __syncthreads();
  }
  #pragma unroll
  for (int i = 0; i < 4; ++i)
    #pragma unroll
    for (int j = 0; j < 4; ++j)
      #pragma unroll
      for (int r = 0; r < 4; ++r) {
        int m = row0 + mb + i*16 + quad*4 + r;
        int n = col0 + nb + j*16 + lane16;
        float v = acc[i][j][r];
        if (MODE == 0) {
          Cf[(size_t)m*N + n] = v;
        } else {
          if (n < 1024)       Cq[(size_t)m*1024 + n] = __float2bfloat16(v);
          else if (n < 1536)  Cf[(size_t)m*512  + n - 1024] = v;
          else                Cv[(size_t)m*2048 + n - 1536] = __float2bfloat16(v);
        }
      }
}

// ---------------- final GEMM: 64x128 tile, BK=64 (512 blocks -> 2/CU) ----------
__global__ __launch_bounds__(256) void gemm_out(const hbf* __restrict__ A,
                                                const hbf* __restrict__ Bt,
                                                float* __restrict__ Cf,
                                                int M, int N, int K) {
  __shared__ hbf As0[64][32], As1[64][32];
  __shared__ hbf Bs0[128][32], Bs1[128][32];
  const int t = threadIdx.x;
  const int w = t >> 6, l = t & 63;
  const int lr = l >> 2;
  const int srcc = (((l & 3) - (l >> 4)) & 3) * 8;
  const int lane16 = l & 15, quad = l >> 4;
  const int sw = (lane16 >> 2) & 3;
  const int row0 = blockIdx.y*64, col0 = blockIdx.x*128;
  const int mb = (w >> 1)*32, nb = (w & 1)*64;

  const hbf* ga = A  + (size_t)(row0 + w*16 + lr)*K + srcc;
  const hbf* gb = Bt + (size_t)(col0 + w*32 + lr)*K + srcc;
  hbf* la0 = &As0[w*16][0];   hbf* la1 = &As1[w*16][0];
  hbf* lb0 = &Bs0[w*32][0];   hbf* lb1 = &Bs0[w*32 + 16][0];
  hbf* lb2 = &Bs1[w*32][0];   hbf* lb3 = &Bs1[w*32 + 16][0];
  const size_t rstep = (size_t)16*K;

  f32x4 acc[2][4] = {};
  for (int k0 = 0; k0 < K; k0 += 64) {
    async_copy16(ga,              la0);
    async_copy16(ga + 32,         la1);
    async_copy16(gb,              lb0);
    async_copy16(gb + rstep,      lb1);
    async_copy16(gb + 32,         lb2);
    async_copy16(gb + rstep + 32, lb3);
    ga += 64; gb += 64;
    __syncthreads();
    {
      bf16x8 af[2], bfr[4];
      #pragma unroll
      for (int i = 0; i < 2; ++i)
        af[i] = *(const bf16x8*)&As0[mb + i*16 + lane16][((quad + sw) & 3)*8];
      #pragma unroll
      for (int j = 0; j < 4; ++j)
        bfr[j] = *(const bf16x8*)&Bs0[nb + j*16 + lane16][((quad + sw) & 3)*8];
      #pragma unroll
      for (int i = 0; i < 2; ++i)
        #pragma unroll
        for (int j = 0; j < 4; ++j)
          acc[i][j] = __builtin_amdgcn_mfma_f32_16x16x32_bf16(af[i], bfr[j], acc[i][j], 0, 0, 0);
    }
    {
      bf16x8 af[2], bfr[4];
      #pragma unroll
      for (int i = 0; i < 2; ++i)
        af[i] = *(const bf16x8*)&As1[mb + i*16 + lane16][((quad + sw) & 3)*8];
      #pragma unroll
      for (int j = 0; j < 4; ++j)
        bfr[j] = *(const bf16x8*)&Bs1[nb + j*16 + lane16][((quad + sw) & 3)*8];
      #pragma unroll
      for (int i = 0; i < 2; ++i)
        #pragma unroll
        for (int j = 0; j < 4; ++j)
          acc[i][j] = __builtin_amdgcn_mfma_f32_16x16x32_bf16(af[i], bfr[j], acc[i][j], 0, 0, 0);
    }
    __syncthreads();
  }
  #pragma unroll
  for (int i = 0; i < 2; ++i)
    #pragma unroll
    for (int j = 0; j < 4; ++j)
      #pragma unroll
      for (int r = 0; r < 4; ++r) {
        int m = row0 + mb + i*16 + quad*4 + r;
        int n = col0 + nb + j*16 + lane16;
        Cf[(size_t)m*N + n] = acc[i][j][r];
      }
}

// ---------------- fused gate + state-chunk (MFMA): per (nc,bh) ----------------
// gate: G=cumsum(logsig(pre+b)/16); emit qg,kg bf16 to global, kbar -> LDS, dec;
// then U[v][k] = v^T kbar via MFMA.  grid: 256 = nc*8 + bh.
__global__ __launch_bounds__(256) void gate_chunk_kernel(const float* __restrict__ Gpre,
                                                         const hbf* __restrict__ qkbf,
                                                         const hbf* __restrict__ vgbf,
                                                         const float* __restrict__ bias,
                                                         hbf* __restrict__ qgb,
                                                         hbf* __restrict__ kgb,
                                                         hbf* __restrict__ Ub,
                                                         float* __restrict__ dec) {
  const int bh = blockIdx.x & 7;
  const int nc = blockIdx.x >> 3;
  const int b = bh >> 2, h = bh & 3;
  const int t = threadIdx.x;
  const int w = t >> 6, l = t & 63;
  const int lane16 = l & 15, quad = l >> 4;
  __shared__ __align__(16) unsigned char smem[55808];
  float (*buf)[128] = (float(*)[128])(smem);            // 32 KB (phase 1-3)
  hbf (*vT)[72]     = (hbf(*)[72])  (smem);             // 36 KB (phase 4, aliases buf)
  hbf (*kbarT)[72]  = (hbf(*)[72])  (smem + 36864);     // 18 KB
  const int bc = b*TDIM + nc*CHUNKC;
  const int col0 = h*DK;
  // phase 1: log-sigmoid
  #pragma unroll
  for (int i = 0; i < 32; ++i) {
    int idx = t + 256*i;
    int c = idx >> 7, kk = idx & 127;
    float s = Gpre[(size_t)(bc + c)*KD + col0 + kk] + bias[col0 + kk];
    buf[c][kk] = (fminf(s, 0.f) - log1pf(expf(-fabsf(s)))) * (1.0f/16.0f);
  }
  __syncthreads();
  // phase 2: cumsum + dec
  if (t < 128) {
    float acc = 0.f;
    #pragma unroll
    for (int c = 0; c < CHUNKC; ++c) { acc += buf[c][t]; buf[c][t] = acc; }
    dec[((size_t)nc*8 + bh)*DK + t] = expf(acc);
  }
  __syncthreads();
  // phase 3: qg/kg to global, kbar to LDS (transposed)
  const float scale = 0.088388347648318447f;  // 128^-0.5
  #pragma unroll
  for (int i = 0; i < 32; ++i) {
    int idx = t + 256*i;
    int c = idx >> 7, kk = idx & 127;
    float g = buf[c][kk], gl = buf[63][kk];
    const size_t qoff = (size_t)(bc + c)*1024 + col0 + kk;
    float qv = __bfloat162float(qkbf[qoff]);
    float kv = __bfloat162float(qkbf[qoff + 512]);
    const size_t ooff = (size_t)(bc + c)*KD + col0 + kk;
    qgb[ooff] = __float2bfloat16(qv * expf(g) * scale);
    kgb[ooff] = __float2bfloat16(kv * expf(-g));
    kbarT[kk][c] = __float2bfloat16(kv * expf(gl - g));
  }
  __syncthreads();
  // phase 4: stage vT over buf region
  #pragma unroll
  for (int i = 0; i < 64; ++i) {
    int idx = t + 256*i;
    int c = idx >> 8, col = idx & 255;
    vT[col][c] = vgbf[(size_t)(bc + c)*2048 + h*DV + col];
  }
  __syncthreads();
  // phase 5: U = v^T @ kbar
  f32x4 acc[4][8] = {};
  #pragma unroll
  for (int kc = 0; kc < 2; ++kc) {
    bf16x8 av[4], bk[8];
    #pragma unroll
    for (int i = 0; i < 4; ++i)
      av[i] = *(const bf16x8*)&vT[w*64 + i*16 + lane16][kc*32 + quad*8];
    #pragma unroll
    for (int j = 0; j < 8; ++j)
      bk[j] = *(const bf16x8*)&kbarT[j*16 + lane16][kc*32 + quad*8];
    #pragma unroll
    for (int i = 0; i < 4; ++i)
      #pragma unroll
      for (int j = 0; j < 8; ++j)
        acc[i][j] = __builtin_amdgcn_mfma_f32_16x16x32_bf16(av[i], bk[j], acc[i][j], 0, 0, 0);
  }
  hbf* ub = Ub + ((size_t)nc*8 + bh)*((size_t)DK*DV);
  #pragma unroll
  for (int i = 0; i < 4; ++i)
    #pragma unroll
    for (int j = 0; j < 8; ++j)
      #pragma unroll
      for (int r = 0; r < 4; ++r) {
        int v = w*64 + i*16 + quad*4 + r;
        int k = j*16 + lane16;
        ub[(size_t)v*DK + k] = __float2bfloat16(acc[i][j][r]);
      }
}

// ---------------- scan over chunks: reads U bf16, fp32 accum, writes S_prev bf16 ----
__global__ __launch_bounds__(256) void state_scan_kernel(const hbf* __restrict__ Ub,
                                                         const float* __restrict__ dec,
                                                         hbf* __restrict__ Spb) {
  const int p = blockIdx.x*256 + threadIdx.x;   // pair index 0..131071
  const size_t e = (size_t)p*2;
  const int k = (int)(e & 127);
  const int bh = (int)(e >> 15);
  float S0 = 0.f, S1 = 0.f;
  for (int nc = 0; nc < NC; ++nc) {
    const size_t off = (size_t)nc*STRIDE_ST + e;
    uint uu = *(const uint*)(Ub + off);
    hbf u0 = *(const hbf*)&uu;
    hbf u1 = *((const hbf*)&uu + 1);
    union { hbf h[2]; uint u; } ov;
    ov.h[0] = __float2bfloat16(S0); ov.h[1] = __float2bfloat16(S1);
    *(uint*)(Spb + off) = ov.u;
    float2 d = *(const float2*)(dec + ((size_t)nc*8 + bh)*DK + k);
    S0 = S0 * d.x + __bfloat162float(u0);
    S1 = S1 * d.y + __bfloat162float(u1);
  }
}

// ---------------- per-chunk output (MFMA): tril(qg kg^T), qg@S + A@v, RMSNorm, gate ----
__global__ __launch_bounds__(256) void out_kernel(const hbf* __restrict__ qgb,
                                                  const hbf* __restrict__ kgb,
                                                  const hbf* __restrict__ vgbf,
                                                  const hbf* __restrict__ Spb,
                                                  const float* __restrict__ gnw,
                                                  hbf* __restrict__ obf) {
  const int blk = blockIdx.x;
  const int h = blk & 3, b = (blk >> 2) & 1, nc = blk >> 3;
  const int t = threadIdx.x;
  const int w = t >> 6, l = t & 63;
  const int lane16 = l & 15, quad = l >> 4;

  __shared__ __align__(16) unsigned char smem[64768];
  hbf (*qgs)[136] = (hbf(*)[136])(smem);                 // 17408 B
  hbf (*Ald)[72]  = (hbf(*)[72]) (smem + 17408);         //  9216 B
  hbf (*kgs)[136] = (hbf(*)[136])(smem + 26624);         // 17408 B (phase 1)
  hbf (*vT)[72]   = (hbf(*)[72]) (smem + 26624);         // 36864 B (phase 2, aliases kgs)
  float* ssum     = (float*)     (smem + 63488);         // 64*4
  float* invb     = (float*)     (smem + 64512);         // 64

  const int bc = b*TDIM + nc*CHUNKC;

  #pragma unroll
  for (int i = 0; i < 4; ++i) {
    int idx = t + 256*i;                 // 1024 chunks of 8 elems
    int c = idx >> 4, ch = (idx & 15)*8;
    *(uint4*)&qgs[c][ch] = *(const uint4*)(qgb + (size_t)(bc + c)*KD + h*DK + ch);
    *(uint4*)&kgs[c][ch] = *(const uint4*)(kgb + (size_t)(bc + c)*KD + h*DK + ch);
  }
  __syncthreads();

  f32x4 acc1[4] = {};
  #pragma unroll
  for (int kc = 0; kc < 4; ++kc) {
    bf16x8 af = *(const bf16x8*)&qgs[w*16 + lane16][kc*32 + quad*8];
    #pragma unroll
    for (int j = 0; j < 4; ++j) {
      bf16x8 bf = *(const bf16x8*)&kgs[j*16 + lane16][kc*32 + quad*8];
      acc1[j] = __builtin_amdgcn_mfma_f32_16x16x32_bf16(af, bf, acc1[j], 0, 0, 0);
    }
  }
  __syncthreads();

  #pragma unroll
  for (int j = 0; j < 4; ++j)
    #pragma unroll
    for (int r = 0; r < 4; ++r) {
      int cr = w*16 + quad*4 + r;
      int cc = j*16 + lane16;
      Ald[cr][cc] = __float2bfloat16(cc <= cr ? acc1[j][r] : 0.f);
    }
  #pragma unroll
  for (int i = 0; i < 64; ++i) {
    int e = t + 256*i;
    int c = e >> 8, col = e & 255;
    vT[col][c] = vgbf[(size_t)(bc + c)*2048 + h*DV + col];
  }
  __syncthreads();

  const hbf* SpB = Spb + ((size_t)nc*8 + (b*HH + h))*((size_t)DK*DV);
  f32x4 acc[4][4] = {};
  #pragma unroll
  for (int kc = 0; kc < 4; ++kc) {
    bf16x8 af[4], bs[4];
    #pragma unroll
    for (int i = 0; i < 4; ++i)
      af[i] = *(const bf16x8*)&qgs[i*16 + lane16][kc*32 + quad*8];
    #pragma unroll
    for (int j = 0; j < 4; ++j) {
      int n = w*64 + j*16 + lane16;
      bs[j] = *(const bf16x8*)(SpB + (size_t)n*DK + kc*32 + quad*8);
    }
    #pragma unroll
    for (int i = 0; i < 4; ++i)
      #pragma unroll
      for (int j = 0; j < 4; ++j)
        acc[i][j] = __builtin_amdgcn_mfma_f32_16x16x32_bf16(af[i], bs[j], acc[i][j], 0, 0, 0);
  }
  #pragma unroll
  for (int kc = 0; kc < 2; ++kc) {
    bf16x8 aa[4], bv[4];
    #pragma unroll
    for (int i = 0; i < 4; ++i)
      aa[i] = *(const bf16x8*)&Ald[i*16 + lane16][kc*32 + quad*8];
    #pragma unroll
    for (int j = 0; j < 4; ++j)
      bv[j] = *(const bf16x8*)&vT[w*64 + j*16 + lane16][kc*32 + quad*8];
    #pragma unroll
    for (int i = 0; i < 4; ++i)
      #pragma unroll
      for (int j = 0; j < 4; ++j)
        acc[i][j] = __builtin_amdgcn_mfma_f32_16x16x32_bf16(aa[i], bv[j], acc[i][j], 0, 0, 0);
  }

  #pragma unroll
  for (int i = 0; i < 4; ++i)
    #pragma unroll
    for (int r = 0; r < 4; ++r) {
      float s = 0.f;
      #pragma unroll
      for (int j = 0; j < 4; ++j) s += acc[i][j][r]*acc[i][j][r];
      s += __shfl_xor(s, 1); s += __shfl_xor(s, 2);
      s += __shfl_xor(s, 4); s += __shfl_xor(s, 8);
      if (lane16 == 0) ssum[(i*16 + quad*4 + r)*4 + w] = s;
    }
  __syncthreads();
  if (t < 64) {
    float tot = ssum[t*4] + ssum[t*4+1] + ssum[t*4+2] + ssum[t*4+3];
    invb[t] = rsqrtf(tot * (1.0f/DV) + 1e-6f);
  }
  __syncthreads();
  float gnwv[4];
  #pragma unroll
  for (int j = 0; j < 4; ++j) gnwv[j] = gnw[w*64 + j*16 + lane16];
  #pragma unroll
  for (int i = 0; i < 4; ++i)
    #pragma unroll
    for (int r = 0; r < 4; ++r) {
      int m = i*16 + quad*4 + r;
      float inv = invb[m];
      size_t grow_ = (size_t)(bc + m)*2048 + 1024 + h*DV + w*64;
      size_t orow_ = (size_t)(bc + m)*VD + h*DV + w*64;
      #pragma unroll
      for (int j = 0; j < 4; ++j) {
        float gv = __bfloat162float(vgbf[grow_ + j*16 + lane16]);
        float sig = 1.f / (1.f + expf(-gv));
        float val = acc[i][j][r] * inv * gnwv[j];
        obf[orow_ + j*16 + lane16] = __float2bfloat16(val * (gv * sig));
      }
    }
}

extern "C" void kernel_launch(void* const* d_in, const int* in_sizes, int n_in,
                              void* d_out, int out_size, void* d_ws, size_t ws_size,
                              hipStream_t stream) {
  const float* x    = (const float*)d_in[0];
  const float* Wq   = (const float*)d_in[1];
  const float* Wk   = (const float*)d_in[2];
  const float* Wv   = (const float*)d_in[3];
  const float* Wg   = (const float*)d_in[4];
  const float* Wgk1 = (const float*)d_in[5];
  const float* Wgk2 = (const float*)d_in[6];
  const float* bgk2 = (const float*)d_in[7];
  const float* gnw  = (const float*)d_in[8];
  const float* Wo   = (const float*)d_in[9];
  float* out = (float*)d_out;

  float* ws  = (float*)d_ws;
  float* Gb  = ws;                                   // 4096*512 fp32 (gk preact)
  float* dec = Gb  + (size_t)MTOT*KD;                // 32*8*128 fp32
  hbf* xbf   = (hbf*)(dec + (size_t)NC*BDIM*HH*DK);  // 4096*1024 bf16
  hbf* wtall = xbf   + (size_t)MTOT*DDIM;            // 3584*1024 bf16
  hbf* wto   = wtall + (size_t)NALL*DDIM;            // 1024*1024 bf16
  hbf* qkbf  = wto   + (size_t)DDIM*DDIM;            // 4096*1024 bf16 (q|k)
  hbf* vgbf  = qkbf  + (size_t)MTOT*1024;            // 4096*2048 bf16 (v|g)
  hbf* qgb   = vgbf  + (size_t)MTOT*2048;            // 4096*512 bf16
  hbf* kgb   = qgb   + (size_t)MTOT*KD;              // 4096*512 bf16
  hbf* Ub    = kgb   + (size_t)MTOT*KD;              // 32*262144 bf16 (U, [v][k])
  hbf* Spb   = Ub    + (size_t)NC*STRIDE_ST;         // 32*262144 bf16 (S_prev, [v][k])
  hbf* obf   = Ub;                                   // alias: U dead before out_kernel

  fused_prep<<<4096 + 4608, 256, 0, stream>>>(x, xbf, Wq, Wk, Wv, Wg, Wo, Wgk1, Wgk2, wtall, wto);

  gemm_bt<1><<<dim3(NALL/128, MTOT/128), 256, 0, stream>>>(xbf, wtall, Gb, qkbf, vgbf, MTOT, NALL, DDIM);

  gate_chunk_kernel<<<NC*BDIM*HH, 256, 0, stream>>>(Gb, qkbf, vgbf, bgk2, qgb, kgb, Ub, dec);
  state_scan_kernel<<<(int)(STRIDE_ST/2/256), 256, 0, stream>>>(Ub, dec, Spb);
  out_kernel<<<NC*BDIM*HH, 256, 0, stream>>>(qgb, kgb, vgbf, Spb, gnw, obf);
  gemm_out<<<dim3(DDIM/128, MTOT/64), 256, 0, stream>>>(obf, wto, out, MTOT, DDIM, DDIM);
}